// Round 9
// baseline (168.920 us; speedup 1.0000x reference)
//
#include <hip/hip_runtime.h>

#define BB 512
#define DD 128
#define HD 64

typedef float v2f __attribute__((ext_vector_type(2)));
#define FMA2(a, b, c) __builtin_elementwise_fma((v2f)(a), (v2f)(b), (v2f)(c))

// ---- workspace layout (float offsets) ----
#define OFF_E1 0                     // 3 * 512 * 128  (normalized emb1, packed (d, d+64))
#define OFF_E2 (3*BB*DD)             // 3 * 512 * 128
#define OFF_C1 (2*3*BB*DD)           // 2 * 512 * 128  (cert1 layers 1,2 packed)
#define OFF_C2 (OFF_C1 + 2*BB*DD)    // 2 * 512 * 128
#define OFF_AB (OFF_C2 + 2*BB*DD)    // 2 layers * (A[128], B[128]); A=-log2e*alpha, B=-log2e*beta
#define OFF_LNK (OFF_AB + 512)       // 2 links * (idx[3][128] RAW dim, w[3][128]) = 2*768
#define WS_FLOATS (OFF_LNK + 1536)   // ~2.51 MB

__device__ __forceinline__ float wave_sum64(float v) {
  #pragma unroll
  for (int off = 1; off < 64; off <<= 1) v += __shfl_xor(v, off, 64);
  return v;
}

// DPP lane-shift add: pure VALU pipe. Sum of all 64 lanes lands in lane 63.
template <int CTRL>
__device__ __forceinline__ float dpp_mov(float x) {
  int i = __builtin_bit_cast(int, x);
  int r = __builtin_amdgcn_update_dpp(0, i, CTRL, 0xF, 0xF, false);
  return __builtin_bit_cast(float, r);
}
__device__ __forceinline__ float dpp_wave_sum_lane63(float v) {
  v += dpp_mov<0x111>(v);  // row_shr:1
  v += dpp_mov<0x112>(v);  // row_shr:2
  v += dpp_mov<0x114>(v);  // row_shr:4
  v += dpp_mov<0x118>(v);  // row_shr:8
  v += dpp_mov<0x142>(v);  // row_bcast:15
  v += dpp_mov<0x143>(v);  // row_bcast:31
  return v;
}

// ---- merged prep ----
// blocks 0..1279: normalize/pack rows (5120 row-tasks, one wave each)
// blocks 1280..1343: link top-3, one wave per (link, column) task (256 tasks)
// R9: indices stored RAW (main derives interleaved/global offsets itself).
struct PackArgs { const float* src[10]; };

__global__ __launch_bounds__(256) void prep_kernel(PackArgs a,
                                                   const float* __restrict__ lnk0,
                                                   const float* __restrict__ lnk1,
                                                   const float* __restrict__ a1,
                                                   const float* __restrict__ b1,
                                                   const float* __restrict__ a2,
                                                   const float* __restrict__ b2,
                                                   float* __restrict__ ws) {
  const int tid  = threadIdx.x;
  const int lane = tid & 63;
  if (blockIdx.x < 1280) {
    const int gw   = blockIdx.x * 4 + (tid >> 6);
    const int arr  = gw >> 9;                       // 0..9
    const int row  = gw & 511;
    const float* s = a.src[arr];
    float lo = s[row * DD + lane];
    float hi = s[row * DD + lane + 64];
    float scale = 1.0f;
    if (arr < 6) {  // embeddings: L2 normalize
      float ss = wave_sum64(lo * lo + hi * hi);
      scale = 1.0f / fmaxf(sqrtf(ss), 1e-12f);
    }
    float* dst;
    if (arr < 3)      dst = ws + OFF_E1 + arr * (BB * DD);
    else if (arr < 6) dst = ws + OFF_E2 + (arr - 3) * (BB * DD);
    else if (arr < 8) dst = ws + OFF_C1 + (arr - 6) * (BB * DD);
    else              dst = ws + OFF_C2 + (arr - 8) * (BB * DD);
    ((float2*)dst)[row * HD + lane] = make_float2(lo * scale, hi * scale);
  } else {
    // one wave per (l, e) column; lane d holds L[d][e] and L[d+64][e]
    const int task = (blockIdx.x - 1280) * 4 + (tid >> 6);   // 0..255
    const int l = task >> 7, e = task & 127;
    const float* L = l ? lnk1 : lnk0;
    float v0 = L[lane * DD + e];
    float v1 = L[(lane + 64) * DD + e];
    float bv[3]; int bd[3];
    #pragma unroll
    for (int k = 0; k < 3; ++k) {
      float lv; int ld;
      if (v0 >= v1) { lv = v0; ld = lane; } else { lv = v1; ld = lane + 64; }
      #pragma unroll
      for (int off = 1; off < 64; off <<= 1) {
        float ov = __shfl_xor(lv, off, 64);
        int   od = __shfl_xor(ld, off, 64);
        if (ov > lv || (ov == lv && od < ld)) { lv = ov; ld = od; }
      }
      bv[k] = lv; bd[k] = ld;             // same in all lanes
      if (ld == lane)      v0 = -1e30f;   // remove winner
      if (ld == lane + 64) v1 = -1e30f;
    }
    if (lane == 0) {
      float inv = 1.0f / (bv[0] + bv[1] + bv[2] + 1e-8f);
      int*   li = (int*)(ws + OFF_LNK + l * 768);
      float* lw =        ws + OFF_LNK + l * 768 + 384;
      li[e] = bd[0]; li[128 + e] = bd[1]; li[256 + e] = bd[2];   // RAW dim index
      lw[e] = bv[0] * inv; lw[128 + e] = bv[1] * inv; lw[256 + e] = bv[2] * inv;
      const float NL2E = -1.4426950408889634f;
      const float* al = l ? a2 : a1;
      const float* bl = l ? b2 : b1;
      ws[OFF_AB + l * 256 + e]       = NL2E * al[e];
      ws[OFF_AB + l * 256 + 128 + e] = NL2E * bl[e];
    }
  }
}

// ---- main: one wave per (i-tile of 4) x (j-chunk of 16); lane owns dims (lane, lane+64).
// R8 post-mortem: 47 us invariant across VALU 45-56% -> LDS pipe bound
// (~9.2 DS ops/pair + 28k conflict cyc/CU). R9 changes:
//  (1) layer-2 gather batches the 4 ii-pairs into float4 LDS words:
//      2 ds_write_b128 + 6 ds_read_b128 per 4 pairs = 2 DS ops/pair (was 7),
//      b128 moves 2x bytes/cycle and its phased access absorbs random-index conflicts.
//  (2) layer-1 setup gathers (fixed indices, amortized) moved to GLOBAL scalar
//      loads (L1/L2-resident rows; VMEM pipe ~idle) -> setup LDS traffic gone.
__global__ __launch_bounds__(256, 4) void main_kernel(const float* __restrict__ ws,
                                                      float* __restrict__ out) {
  __shared__ float4 pbuf[4][DD];         // per-wave pair-buffer: pbuf[d] = h1_{ii0..3}[d]
  const int tid  = threadIdx.x;
  const int lane = tid & 63;
  const int w    = tid >> 6;
  float4* pb = pbuf[w];
  const int gw = blockIdx.x * 4 + w;     // 4096 waves
  const int i0 = (gw >> 5) * 4;          // 128 i-tiles of 4
  const int j0 = (gw & 31) * 16;         // 32 j-chunks of 16

  const int*   li0 = (const int*)(ws + OFF_LNK);
  const float* lw0 = ws + OFF_LNK + 384;
  const int*   li1 = (const int*)(ws + OFF_LNK + 768);
  const float* lw1 = ws + OFF_LNK + 768 + 384;
  // layer-1: interleaved row-offsets (element d of a packed row is at ((d&63)<<1)|(d>>6))
  // layer-2: raw dim index into pbuf
  int J1[3][2], S2[3][2]; v2f W1[3], W2[3];
  #pragma unroll
  for (int k = 0; k < 3; ++k) {
    int sx = li0[k * 128 + lane], sy = li0[k * 128 + lane + 64];
    J1[k][0] = ((sx & 63) << 1) | (sx >> 6);
    J1[k][1] = ((sy & 63) << 1) | (sy >> 6);
    W1[k].x  = lw0[k * 128 + lane]; W1[k].y = lw0[k * 128 + lane + 64];
    S2[k][0] = li1[k * 128 + lane];
    S2[k][1] = li1[k * 128 + lane + 64];
    W2[k].x  = lw1[k * 128 + lane]; W2[k].y = lw1[k * 128 + lane + 64];
  }
  v2f Av1, Bv1, Av2, Bv2;
  Av1.x = ws[OFF_AB + lane];       Av1.y = ws[OFF_AB + lane + 64];
  Bv1.x = ws[OFF_AB + 128 + lane]; Bv1.y = ws[OFF_AB + 128 + lane + 64];
  Av2.x = ws[OFF_AB + 256 + lane]; Av2.y = ws[OFF_AB + 256 + lane + 64];
  Bv2.x = ws[OFF_AB + 384 + lane]; Bv2.y = ws[OFF_AB + 384 + lane + 64];

  const float2* E1p = (const float2*)(ws + OFF_E1);
  const float2* E2p = (const float2*)(ws + OFF_E2);
  const float2* C1p = (const float2*)(ws + OFF_C1);
  const float2* C2p = (const float2*)(ws + OFF_C2);
  #define LD2(p, idx) ({ float2 _t = (p)[idx]; v2f _v; _v.x = _t.x; _v.y = _t.y; _v; })

  // i-tile setup: u0 gathered at layer-1 indices via GLOBAL loads (row L2-resident)
  v2f U[4][3];            // -2*w1_k*u0[d_k]
  v2f SU[4];              // Sum_k w1_k*u0[d_k]^2
  v2f u1[4], u2[4], c11[4], c12[4];
  #pragma unroll
  for (int ii = 0; ii < 4; ++ii) {
    const int i = i0 + ii;
    const float* r0 = ws + OFF_E1 + i * DD;       // layer-0 row i (interleaved)
    SU[ii] = (v2f)0.0f;
    #pragma unroll
    for (int k = 0; k < 3; ++k) {
      v2f a; a.x = r0[J1[k][0]]; a.y = r0[J1[k][1]];
      v2f t = W1[k] * a;
      SU[ii] = FMA2(t, a, SU[ii]);
      U[ii][k] = -2.0f * t;
    }
    u1[ii]  = LD2(E1p, (1 * BB + i) * HD + lane);
    u2[ii]  = LD2(E1p, (2 * BB + i) * HD + lane);
    c11[ii] = LD2(C1p, (0 * BB + i) * HD + lane);
    c12[ii] = LD2(C1p, (1 * BB + i) * HD + lane);
  }

  #pragma unroll 1
  for (int jj = 0; jj < 16; ++jj) {
    const int j = j0 + jj;
    // layer-1 v0 gather via GLOBAL loads from the packed row (L1/L2-hit)
    const float* r0 = ws + OFF_E2 + j * DD;
    v2f V[3], SV = (v2f)0.0f;
    #pragma unroll
    for (int k = 0; k < 3; ++k) {
      v2f c; c.x = r0[J1[k][0]]; c.y = r0[J1[k][1]];
      V[k] = c;
      SV = FMA2(W1[k] * c, c, SV);
    }
    const v2f v1  = LD2(E2p, (1 * BB + j) * HD + lane);
    const v2f v2  = LD2(E2p, (2 * BB + j) * HD + lane);
    const v2f g21 = LD2(C2p, (0 * BB + j) * HD + lane);
    const v2f g22 = LD2(C2p, (1 * BB + j) * HD + lane);

    // ---- layer 1 for all 4 pairs (registers only) ----
    v2f h1v[4];
    #pragma unroll
    for (int ii = 0; ii < 4; ++ii) {
      v2f g1 = FMA2(U[ii][0], V[0], FMA2(U[ii][1], V[1], FMA2(U[ii][2], V[2], SU[ii] + SV)));
      v2f d1 = u1[ii] - v1;
      v2f n1 = d1 * d1;
      v2f x1 = FMA2(c11[ii] * g21, Av1, Bv1);
      v2f t1, P1;
      t1.x = __builtin_amdgcn_exp2f(x1.x); t1.y = __builtin_amdgcn_exp2f(x1.y);
      P1.x = __builtin_amdgcn_rcpf(1.0f + t1.x); P1.y = __builtin_amdgcn_rcpf(1.0f + t1.y);
      h1v[ii] = FMA2(P1, n1 - g1, g1);           // (1-P)*g + P*n
    }
    // ---- batched layer-2 gather: 2 x ds_write_b128 + 6 x ds_read_b128 per 4 pairs ----
    float4 xs, ys;
    xs.x = h1v[0].x; xs.y = h1v[1].x; xs.z = h1v[2].x; xs.w = h1v[3].x;
    ys.x = h1v[0].y; ys.y = h1v[1].y; ys.z = h1v[2].y; ys.w = h1v[3].y;
    pb[lane] = xs;            // dims 0..63   (same-wave DS: in-order, no barrier)
    pb[lane + 64] = ys;       // dims 64..127
    v2f g2[4];
    g2[0] = (v2f)0.0f; g2[1] = (v2f)0.0f; g2[2] = (v2f)0.0f; g2[3] = (v2f)0.0f;
    #pragma unroll
    for (int k = 0; k < 3; ++k) {
      float4 ql = pb[S2[k][0]];    // h1_{ii0..3}[src dim for e=lane]
      float4 qh = pb[S2[k][1]];    // h1_{ii0..3}[src dim for e=lane+64]
      v2f t0; t0.x = ql.x; t0.y = qh.x; g2[0] = FMA2(W2[k], t0, g2[0]);
      v2f t1; t1.x = ql.y; t1.y = qh.y; g2[1] = FMA2(W2[k], t1, g2[1]);
      v2f t2; t2.x = ql.z; t2.y = qh.z; g2[2] = FMA2(W2[k], t2, g2[2]);
      v2f t3; t3.x = ql.w; t3.y = qh.w; g2[3] = FMA2(W2[k], t3, g2[3]);
    }
    // ---- layer 2 + reduction per pair ----
    #pragma unroll
    for (int ii = 0; ii < 4; ++ii) {
      v2f d2 = u2[ii] - v2;
      v2f n2 = d2 * d2;
      v2f x2 = FMA2(c12[ii] * g22, Av2, Bv2);
      v2f t2, P2;
      t2.x = __builtin_amdgcn_exp2f(x2.x); t2.y = __builtin_amdgcn_exp2f(x2.y);
      P2.x = __builtin_amdgcn_rcpf(1.0f + t2.x); P2.y = __builtin_amdgcn_rcpf(1.0f + t2.y);
      v2f h2 = FMA2(P2, n2 - g2[ii], g2[ii]);
      float s = dpp_wave_sum_lane63(h2.x + h2.y);
      if (lane == 63) out[(i0 + ii) * BB + j] = s;
    }
  }
}

extern "C" void kernel_launch(void* const* d_in, const int* in_sizes, int n_in,
                              void* d_out, int out_size, void* d_ws, size_t ws_size,
                              hipStream_t stream) {
  (void)in_sizes; (void)n_in; (void)out_size; (void)ws_size;
  // dict order: [0]emb1_0 [1]emb2_0 [2]cert1_0 [3]cert2_0 [4]alpha_0 [5]beta_0
  //             [6..11] layer1, [12..17] layer2, [18]link_0 [19]link_1
  float* ws = (float*)d_ws;
  PackArgs pa;
  pa.src[0] = (const float*)d_in[0];  pa.src[1] = (const float*)d_in[6];  pa.src[2] = (const float*)d_in[12];
  pa.src[3] = (const float*)d_in[1];  pa.src[4] = (const float*)d_in[7];  pa.src[5] = (const float*)d_in[13];
  pa.src[6] = (const float*)d_in[8];  pa.src[7] = (const float*)d_in[14];
  pa.src[8] = (const float*)d_in[9];  pa.src[9] = (const float*)d_in[15];
  hipLaunchKernelGGL(prep_kernel, dim3(1344), dim3(256), 0, stream, pa,
                     (const float*)d_in[18], (const float*)d_in[19],
                     (const float*)d_in[10], (const float*)d_in[11],
                     (const float*)d_in[16], (const float*)d_in[17], ws);
  hipLaunchKernelGGL(main_kernel, dim3(1024), dim3(256), 0, stream,
                     (const float*)ws, (float*)d_out);
}

// Round 11
// 138.431 us; speedup vs baseline: 1.2202x; 1.2202x over previous
//
#include <hip/hip_runtime.h>

#define BB 512
#define DD 128
#define HD 64

typedef float v2f __attribute__((ext_vector_type(2)));
#define FMA2(a, b, c) __builtin_elementwise_fma((v2f)(a), (v2f)(b), (v2f)(c))

// ---- workspace layout (float offsets) ----
#define OFF_E1 0                     // 3 * 512 * 128  (normalized emb1, packed (d, d+64))
#define OFF_E2 (3*BB*DD)             // 3 * 512 * 128
#define OFF_C1 (2*3*BB*DD)           // 2 * 512 * 128  (cert1 layers 1,2 packed)
#define OFF_C2 (OFF_C1 + 2*BB*DD)    // 2 * 512 * 128
#define OFF_AB (OFF_C2 + 2*BB*DD)    // 2 layers * (A[128], B[128]); A=-log2e*alpha, B=-log2e*beta
#define OFF_LNK (OFF_AB + 512)       // 2 links * (idx[3][128] RAW dim, w[3][128]) = 2*768
#define WS_FLOATS (OFF_LNK + 1536)   // ~2.51 MB

__device__ __forceinline__ float wave_sum64(float v) {
  #pragma unroll
  for (int off = 1; off < 64; off <<= 1) v += __shfl_xor(v, off, 64);
  return v;
}

// DPP lane-shift add: pure VALU pipe. Sum of all 64 lanes lands in lane 63.
template <int CTRL>
__device__ __forceinline__ float dpp_mov(float x) {
  int i = __builtin_bit_cast(int, x);
  int r = __builtin_amdgcn_update_dpp(0, i, CTRL, 0xF, 0xF, false);
  return __builtin_bit_cast(float, r);
}
__device__ __forceinline__ float dpp_wave_sum_lane63(float v) {
  v += dpp_mov<0x111>(v);  // row_shr:1
  v += dpp_mov<0x112>(v);  // row_shr:2
  v += dpp_mov<0x114>(v);  // row_shr:4
  v += dpp_mov<0x118>(v);  // row_shr:8
  v += dpp_mov<0x142>(v);  // row_bcast:15
  v += dpp_mov<0x143>(v);  // row_bcast:31
  return v;
}

// ---- merged prep (R9/R10 version — correctness-verified by R9) ----
// blocks 0..1279: normalize/pack rows (5120 row-tasks, one wave each)
// blocks 1280..1343: link top-3, one wave per (link, column) task; RAW indices stored.
struct PackArgs { const float* src[10]; };

__global__ __launch_bounds__(256) void prep_kernel(PackArgs a,
                                                   const float* __restrict__ lnk0,
                                                   const float* __restrict__ lnk1,
                                                   const float* __restrict__ a1,
                                                   const float* __restrict__ b1,
                                                   const float* __restrict__ a2,
                                                   const float* __restrict__ b2,
                                                   float* __restrict__ ws) {
  const int tid  = threadIdx.x;
  const int lane = tid & 63;
  if (blockIdx.x < 1280) {
    const int gw   = blockIdx.x * 4 + (tid >> 6);
    const int arr  = gw >> 9;                       // 0..9
    const int row  = gw & 511;
    const float* s = a.src[arr];
    float lo = s[row * DD + lane];
    float hi = s[row * DD + lane + 64];
    float scale = 1.0f;
    if (arr < 6) {  // embeddings: L2 normalize
      float ss = wave_sum64(lo * lo + hi * hi);
      scale = 1.0f / fmaxf(sqrtf(ss), 1e-12f);
    }
    float* dst;
    if (arr < 3)      dst = ws + OFF_E1 + arr * (BB * DD);
    else if (arr < 6) dst = ws + OFF_E2 + (arr - 3) * (BB * DD);
    else if (arr < 8) dst = ws + OFF_C1 + (arr - 6) * (BB * DD);
    else              dst = ws + OFF_C2 + (arr - 8) * (BB * DD);
    ((float2*)dst)[row * HD + lane] = make_float2(lo * scale, hi * scale);
  } else {
    // one wave per (l, e) column; lane d holds L[d][e] and L[d+64][e]
    const int task = (blockIdx.x - 1280) * 4 + (tid >> 6);   // 0..255
    const int l = task >> 7, e = task & 127;
    const float* L = l ? lnk1 : lnk0;
    float v0 = L[lane * DD + e];
    float v1 = L[(lane + 64) * DD + e];
    float bv[3]; int bd[3];
    #pragma unroll
    for (int k = 0; k < 3; ++k) {
      float lv; int ld;
      if (v0 >= v1) { lv = v0; ld = lane; } else { lv = v1; ld = lane + 64; }
      #pragma unroll
      for (int off = 1; off < 64; off <<= 1) {
        float ov = __shfl_xor(lv, off, 64);
        int   od = __shfl_xor(ld, off, 64);
        if (ov > lv || (ov == lv && od < ld)) { lv = ov; ld = od; }
      }
      bv[k] = lv; bd[k] = ld;             // same in all lanes
      if (ld == lane)      v0 = -1e30f;   // remove winner
      if (ld == lane + 64) v1 = -1e30f;
    }
    if (lane == 0) {
      float inv = 1.0f / (bv[0] + bv[1] + bv[2] + 1e-8f);
      int*   li = (int*)(ws + OFF_LNK + l * 768);
      float* lw =        ws + OFF_LNK + l * 768 + 384;
      li[e] = bd[0]; li[128 + e] = bd[1]; li[256 + e] = bd[2];   // RAW dim index
      lw[e] = bv[0] * inv; lw[128 + e] = bv[1] * inv; lw[256 + e] = bv[2] * inv;
      const float NL2E = -1.4426950408889634f;
      const float* al = l ? a2 : a1;
      const float* bl = l ? b2 : b1;
      ws[OFF_AB + l * 256 + e]       = NL2E * al[e];
      ws[OFF_AB + l * 256 + 128 + e] = NL2E * bl[e];
    }
  }
}

// ---- main: R8 skeleton; ONE structural change: per-pair layer-2 LDS planes.
// h1 of pair ii lives in plane pw[128*ii .. 128*ii+127] (plain layout, bank=d%32).
// Writes: 2 b32/pair at bank lane%32 -> 2-way aliasing = free (m136).
// Reads: the 3 source dims per output dim are IDENTICAL across the 4 ii-pairs,
// and planes are 128 dwords apart -> pw[s] / pw[s+128] merge into ds_read2_b32
// (offset1=128 fits 8-bit field): 12 read-instrs per 4 pairs instead of 24.
// R10 post-mortem: ds_bpermute gather is wrong on gfx950 (identical absmax
// 0.375 in R7+R10) — permanently abandoned.
// amdgpu_waves_per_eu(4,4): pin occupancy target at 4 waves/EU (128-VGPR
// budget) so the allocator doesn't squeeze to 64 and spill like R9.
__global__ __launch_bounds__(256)
__attribute__((amdgpu_waves_per_eu(4, 4)))
void main_kernel(const float* __restrict__ ws, float* __restrict__ out) {
  __shared__ float hbuf[4][DD];          // setup-gather buffer (R8-verified pattern)
  __shared__ float pbuf[4][4 * DD];      // per-wave, per-pair h1 planes
  const int tid  = threadIdx.x;
  const int lane = tid & 63;
  const int w    = tid >> 6;
  float*  hb  = hbuf[w];
  float2* hb2 = (float2*)hb;             // hb2[l] = (dim l, dim l+64)
  float*  pw  = pbuf[w];
  const int gw = blockIdx.x * 4 + w;     // 4096 waves
  const int i0 = (gw >> 5) * 4;          // 128 i-tiles of 4
  const int j0 = (gw & 31) * 16;         // 32 j-chunks of 16

  const int*   li0 = (const int*)(ws + OFF_LNK);
  const float* lw0 = ws + OFF_LNK + 384;
  const int*   li1 = (const int*)(ws + OFF_LNK + 768);
  const float* lw1 = ws + OFF_LNK + 768 + 384;
  // layer-1: LDS word offsets (dim d lives at ((d&63)<<1)|(d>>6) in hbuf)
  // layer-2: raw source dim into the h1 planes
  int J1[3][2], S2[3][2]; v2f W1[3], W2[3];
  #pragma unroll
  for (int k = 0; k < 3; ++k) {
    int sx = li0[k * 128 + lane], sy = li0[k * 128 + lane + 64];
    J1[k][0] = ((sx & 63) << 1) | (sx >> 6);
    J1[k][1] = ((sy & 63) << 1) | (sy >> 6);
    W1[k].x  = lw0[k * 128 + lane]; W1[k].y = lw0[k * 128 + lane + 64];
    S2[k][0] = li1[k * 128 + lane];
    S2[k][1] = li1[k * 128 + lane + 64];
    W2[k].x  = lw1[k * 128 + lane]; W2[k].y = lw1[k * 128 + lane + 64];
  }
  v2f Av1, Bv1, Av2, Bv2;
  Av1.x = ws[OFF_AB + lane];       Av1.y = ws[OFF_AB + lane + 64];
  Bv1.x = ws[OFF_AB + 128 + lane]; Bv1.y = ws[OFF_AB + 128 + lane + 64];
  Av2.x = ws[OFF_AB + 256 + lane]; Av2.y = ws[OFF_AB + 256 + lane + 64];
  Bv2.x = ws[OFF_AB + 384 + lane]; Bv2.y = ws[OFF_AB + 384 + lane + 64];

  const float2* E1p = (const float2*)(ws + OFF_E1);
  const float2* E2p = (const float2*)(ws + OFF_E2);
  const float2* C1p = (const float2*)(ws + OFF_C1);
  const float2* C2p = (const float2*)(ws + OFF_C2);
  #define LD2(p, idx) ({ float2 _t = (p)[idx]; v2f _v; _v.x = _t.x; _v.y = _t.y; _v; })

  // i-tile setup: gather u0 at layer-1 indices via LDS (R8 pattern, amortized)
  v2f U[4][3];            // -2*w1_k*u0[d_k]
  v2f SU[4];              // Sum_k w1_k*u0[d_k]^2
  v2f u1[4], u2[4], c11[4], c12[4];
  #pragma unroll
  for (int ii = 0; ii < 4; ++ii) {
    const int i = i0 + ii;
    float2 u0 = E1p[(0 * BB + i) * HD + lane];
    hb2[lane] = u0;                               // same-wave DS: in-order, no barrier
    SU[ii] = (v2f)0.0f;
    #pragma unroll
    for (int k = 0; k < 3; ++k) {
      v2f a; a.x = hb[J1[k][0]]; a.y = hb[J1[k][1]];
      v2f t = W1[k] * a;
      SU[ii] = FMA2(t, a, SU[ii]);
      U[ii][k] = -2.0f * t;
    }
    u1[ii]  = LD2(E1p, (1 * BB + i) * HD + lane);
    u2[ii]  = LD2(E1p, (2 * BB + i) * HD + lane);
    c11[ii] = LD2(C1p, (0 * BB + i) * HD + lane);
    c12[ii] = LD2(C1p, (1 * BB + i) * HD + lane);
  }

  #pragma unroll 1
  for (int jj = 0; jj < 16; ++jj) {
    const int j = j0 + jj;
    float2 v0 = E2p[(0 * BB + j) * HD + lane];
    hb2[lane] = v0;
    v2f V[3], SV = (v2f)0.0f;
    #pragma unroll
    for (int k = 0; k < 3; ++k) {
      v2f c; c.x = hb[J1[k][0]]; c.y = hb[J1[k][1]];
      V[k] = c;
      SV = FMA2(W1[k] * c, c, SV);
    }
    const v2f v1  = LD2(E2p, (1 * BB + j) * HD + lane);
    const v2f v2  = LD2(E2p, (2 * BB + j) * HD + lane);
    const v2f g21 = LD2(C2p, (0 * BB + j) * HD + lane);
    const v2f g22 = LD2(C2p, (1 * BB + j) * HD + lane);

    // ---- layer 1: compute h1 per pair, write straight into its plane ----
    #pragma unroll
    for (int ii = 0; ii < 4; ++ii) {
      v2f g1 = FMA2(U[ii][0], V[0], FMA2(U[ii][1], V[1], FMA2(U[ii][2], V[2], SU[ii] + SV)));
      v2f d1 = u1[ii] - v1;
      v2f n1 = d1 * d1;
      v2f x1 = FMA2(c11[ii] * g21, Av1, Bv1);
      v2f t1, P1;
      t1.x = __builtin_amdgcn_exp2f(x1.x); t1.y = __builtin_amdgcn_exp2f(x1.y);
      P1.x = __builtin_amdgcn_rcpf(1.0f + t1.x); P1.y = __builtin_amdgcn_rcpf(1.0f + t1.y);
      v2f h1 = FMA2(P1, n1 - g1, g1);           // (1-P)*g + P*n
      pw[ii * DD + lane]      = h1.x;           // bank = lane%32: 2-way, free
      pw[ii * DD + 64 + lane] = h1.y;
    }
    // ---- layer-2 gather: same source dim across all 4 planes -> ds_read2_b32 ----
    v2f g2[4];
    g2[0] = (v2f)0.0f; g2[1] = (v2f)0.0f; g2[2] = (v2f)0.0f; g2[3] = (v2f)0.0f;
    #pragma unroll
    for (int k = 0; k < 3; ++k) {
      const int slo = S2[k][0], shi = S2[k][1];
      float a0 = pw[slo];           float a1 = pw[slo + DD];
      float a2 = pw[slo + 2 * DD];  float a3 = pw[slo + 3 * DD];
      float b0 = pw[shi];           float b1 = pw[shi + DD];
      float b2 = pw[shi + 2 * DD];  float b3 = pw[shi + 3 * DD];
      v2f t0; t0.x = a0; t0.y = b0; g2[0] = FMA2(W2[k], t0, g2[0]);
      v2f t1; t1.x = a1; t1.y = b1; g2[1] = FMA2(W2[k], t1, g2[1]);
      v2f t2; t2.x = a2; t2.y = b2; g2[2] = FMA2(W2[k], t2, g2[2]);
      v2f t3; t3.x = a3; t3.y = b3; g2[3] = FMA2(W2[k], t3, g2[3]);
    }
    // ---- layer 2 blend + reduction per pair ----
    #pragma unroll
    for (int ii = 0; ii < 4; ++ii) {
      v2f d2 = u2[ii] - v2;
      v2f n2 = d2 * d2;
      v2f x2 = FMA2(c12[ii] * g22, Av2, Bv2);
      v2f t2, P2;
      t2.x = __builtin_amdgcn_exp2f(x2.x); t2.y = __builtin_amdgcn_exp2f(x2.y);
      P2.x = __builtin_amdgcn_rcpf(1.0f + t2.x); P2.y = __builtin_amdgcn_rcpf(1.0f + t2.y);
      v2f h2 = FMA2(P2, n2 - g2[ii], g2[ii]);
      float s = dpp_wave_sum_lane63(h2.x + h2.y);
      if (lane == 63) out[(i0 + ii) * BB + j] = s;
    }
  }
}

extern "C" void kernel_launch(void* const* d_in, const int* in_sizes, int n_in,
                              void* d_out, int out_size, void* d_ws, size_t ws_size,
                              hipStream_t stream) {
  (void)in_sizes; (void)n_in; (void)out_size; (void)ws_size;
  // dict order: [0]emb1_0 [1]emb2_0 [2]cert1_0 [3]cert2_0 [4]alpha_0 [5]beta_0
  //             [6..11] layer1, [12..17] layer2, [18]link_0 [19]link_1
  float* ws = (float*)d_ws;
  PackArgs pa;
  pa.src[0] = (const float*)d_in[0];  pa.src[1] = (const float*)d_in[6];  pa.src[2] = (const float*)d_in[12];
  pa.src[3] = (const float*)d_in[1];  pa.src[4] = (const float*)d_in[7];  pa.src[5] = (const float*)d_in[13];
  pa.src[6] = (const float*)d_in[8];  pa.src[7] = (const float*)d_in[14];
  pa.src[8] = (const float*)d_in[9];  pa.src[9] = (const float*)d_in[15];
  hipLaunchKernelGGL(prep_kernel, dim3(1344), dim3(256), 0, stream, pa,
                     (const float*)d_in[18], (const float*)d_in[19],
                     (const float*)d_in[10], (const float*)d_in[11],
                     (const float*)d_in[16], (const float*)d_in[17], ws);
  hipLaunchKernelGGL(main_kernel, dim3(1024), dim3(256), 0, stream,
                     (const float*)ws, (float*)d_out);
}

// Round 12
// 134.187 us; speedup vs baseline: 1.2588x; 1.0316x over previous
//
#include <hip/hip_runtime.h>

#define BB 512
#define DD 128
#define HD 64

typedef float v2f __attribute__((ext_vector_type(2)));
#define FMA2(a, b, c) __builtin_elementwise_fma((v2f)(a), (v2f)(b), (v2f)(c))

// ---- workspace layout (float offsets) ----
#define OFF_E1 0                     // 3 * 512 * 128  (normalized emb1, packed (d, d+64))
#define OFF_E2 (3*BB*DD)             // 3 * 512 * 128
#define OFF_C1 (2*3*BB*DD)           // 2 * 512 * 128  (cert1 layers 1,2 packed)
#define OFF_C2 (OFF_C1 + 2*BB*DD)    // 2 * 512 * 128
#define OFF_AB (OFF_C2 + 2*BB*DD)    // 2 layers * (A[128], B[128]); A=-log2e*alpha, B=-log2e*beta
#define OFF_LNK (OFF_AB + 512)       // 2 links * (idx[3][128] interleaved, w[3][128]) = 2*768
#define WS_FLOATS (OFF_LNK + 1536)   // ~2.51 MB

__device__ __forceinline__ float wave_sum64(float v) {
  #pragma unroll
  for (int off = 1; off < 64; off <<= 1) v += __shfl_xor(v, off, 64);
  return v;
}

// DPP lane-shift add: pure VALU pipe. Sum of all 64 lanes lands in lane 63.
template <int CTRL>
__device__ __forceinline__ float dpp_mov(float x) {
  int i = __builtin_bit_cast(int, x);
  int r = __builtin_amdgcn_update_dpp(0, i, CTRL, 0xF, 0xF, false);
  return __builtin_bit_cast(float, r);
}
__device__ __forceinline__ float dpp_wave_sum_lane63(float v) {
  v += dpp_mov<0x111>(v);  // row_shr:1
  v += dpp_mov<0x112>(v);  // row_shr:2
  v += dpp_mov<0x114>(v);  // row_shr:4
  v += dpp_mov<0x118>(v);  // row_shr:8
  v += dpp_mov<0x142>(v);  // row_bcast:15
  v += dpp_mov<0x143>(v);  // row_bcast:31
  return v;
}

// ---- merged prep ----
// R12: link blocks FIRST (blockIdx 0..63) so their uncoalesced column loads
// overlap the pack waves instead of forming a dispatch tail.
// blocks 64..1343: normalize/pack rows (5120 row-tasks, one wave each)
struct PackArgs { const float* src[10]; };

__global__ __launch_bounds__(256) void prep_kernel(PackArgs a,
                                                   const float* __restrict__ lnk0,
                                                   const float* __restrict__ lnk1,
                                                   const float* __restrict__ a1,
                                                   const float* __restrict__ b1,
                                                   const float* __restrict__ a2,
                                                   const float* __restrict__ b2,
                                                   float* __restrict__ ws) {
  const int tid  = threadIdx.x;
  const int lane = tid & 63;
  if (blockIdx.x >= 64) {
    const int gw   = (blockIdx.x - 64) * 4 + (tid >> 6);
    const int arr  = gw >> 9;                       // 0..9
    const int row  = gw & 511;
    const float* s = a.src[arr];
    float lo = s[row * DD + lane];
    float hi = s[row * DD + lane + 64];
    float scale = 1.0f;
    if (arr < 6) {  // embeddings: L2 normalize
      float ss = wave_sum64(lo * lo + hi * hi);
      scale = 1.0f / fmaxf(sqrtf(ss), 1e-12f);
    }
    float* dst;
    if (arr < 3)      dst = ws + OFF_E1 + arr * (BB * DD);
    else if (arr < 6) dst = ws + OFF_E2 + (arr - 3) * (BB * DD);
    else if (arr < 8) dst = ws + OFF_C1 + (arr - 6) * (BB * DD);
    else              dst = ws + OFF_C2 + (arr - 8) * (BB * DD);
    ((float2*)dst)[row * HD + lane] = make_float2(lo * scale, hi * scale);
  } else {
    // one wave per (l, e) column; lane d holds L[d][e] and L[d+64][e]
    const int task = blockIdx.x * 4 + (tid >> 6);   // 0..255
    const int l = task >> 7, e = task & 127;
    const float* L = l ? lnk1 : lnk0;
    float v0 = L[lane * DD + e];
    float v1 = L[(lane + 64) * DD + e];
    float bv[3]; int bd[3];
    #pragma unroll
    for (int k = 0; k < 3; ++k) {
      float lv; int ld;
      if (v0 >= v1) { lv = v0; ld = lane; } else { lv = v1; ld = lane + 64; }
      #pragma unroll
      for (int off = 1; off < 64; off <<= 1) {
        float ov = __shfl_xor(lv, off, 64);
        int   od = __shfl_xor(ld, off, 64);
        if (ov > lv || (ov == lv && od < ld)) { lv = ov; ld = od; }
      }
      bv[k] = lv; bd[k] = ld;             // same in all lanes
      if (ld == lane)      v0 = -1e30f;   // remove winner
      if (ld == lane + 64) v1 = -1e30f;
    }
    if (lane == 0) {
      float inv = 1.0f / (bv[0] + bv[1] + bv[2] + 1e-8f);
      int*   li = (int*)(ws + OFF_LNK + l * 768);
      float* lw =        ws + OFF_LNK + l * 768 + 384;
      // indices pre-transformed for interleaved LDS h-layout:
      // dim d lives at LDS word ((d&63)<<1) | (d>>6)
      li[e]       = ((bd[0] & 63) << 1) | (bd[0] >> 6);
      li[128 + e] = ((bd[1] & 63) << 1) | (bd[1] >> 6);
      li[256 + e] = ((bd[2] & 63) << 1) | (bd[2] >> 6);
      lw[e] = bv[0] * inv; lw[128 + e] = bv[1] * inv; lw[256 + e] = bv[2] * inv;
      const float NL2E = -1.4426950408889634f;
      const float* al = l ? a2 : a1;
      const float* bl = l ? b2 : b1;
      ws[OFF_AB + l * 256 + e]       = NL2E * al[e];
      ws[OFF_AB + l * 256 + 128 + e] = NL2E * bl[e];
    }
  }
}

// ---- main: EXACT R8 kernel (verified best: 47.0 us, absmax 0.0).
// One wave per (i-tile of 4) x (j-chunk of 16); lane owns dims (lane, lane+64)
// packed in v2f (v_pk_fma_f32); layer-1 gather register-factored; layer-2 gather
// via the verified float2-store/float-load LDS round-trip.
// R11 post-mortem: per-pair LDS planes + ds_read2 raised conflicts (8.0e6) and
// spilled mildly (WRITE 11 MB) — reverted. R7/R10: ds_bpermute wrong on gfx950
// (identical absmax 0.375 twice) — abandoned.
__global__ __launch_bounds__(256, 4) void main_kernel(const float* __restrict__ ws,
                                                      float* __restrict__ out) {
  __shared__ float hbuf[4][DD];
  const int tid  = threadIdx.x;
  const int lane = tid & 63;
  const int w    = tid >> 6;
  float*  hb  = hbuf[w];
  float2* hb2 = (float2*)hb;             // hb2[l] = (dim l, dim l+64)  [R6/R8-verified]
  const int gw = blockIdx.x * 4 + w;     // 4096 waves
  const int i0 = (gw >> 5) * 4;          // 128 i-tiles of 4
  const int j0 = (gw & 31) * 16;         // 32 j-chunks of 16

  const int*   li0 = (const int*)(ws + OFF_LNK);
  const float* lw0 = ws + OFF_LNK + 384;
  const int*   li1 = (const int*)(ws + OFF_LNK + 768);
  const float* lw1 = ws + OFF_LNK + 768 + 384;
  int I1[3][2], I2[3][2]; v2f W1[3], W2[3];
  #pragma unroll
  for (int k = 0; k < 3; ++k) {
    I1[k][0] = li0[k * 128 + lane]; I1[k][1] = li0[k * 128 + lane + 64];
    W1[k].x  = lw0[k * 128 + lane]; W1[k].y  = lw0[k * 128 + lane + 64];
    I2[k][0] = li1[k * 128 + lane]; I2[k][1] = li1[k * 128 + lane + 64];
    W2[k].x  = lw1[k * 128 + lane]; W2[k].y  = lw1[k * 128 + lane + 64];
  }
  v2f Av1, Bv1, Av2, Bv2;
  Av1.x = ws[OFF_AB + lane];       Av1.y = ws[OFF_AB + lane + 64];
  Bv1.x = ws[OFF_AB + 128 + lane]; Bv1.y = ws[OFF_AB + 128 + lane + 64];
  Av2.x = ws[OFF_AB + 256 + lane]; Av2.y = ws[OFF_AB + 256 + lane + 64];
  Bv2.x = ws[OFF_AB + 384 + lane]; Bv2.y = ws[OFF_AB + 384 + lane + 64];

  const float2* E1p = (const float2*)(ws + OFF_E1);
  const float2* E2p = (const float2*)(ws + OFF_E2);
  const float2* C1p = (const float2*)(ws + OFF_C1);
  const float2* C2p = (const float2*)(ws + OFF_C2);
  #define LD2(p, idx) ({ float2 _t = (p)[idx]; v2f _v; _v.x = _t.x; _v.y = _t.y; _v; })

  // i-tile setup: gather u0 at layer-1 indices once per ii (amortized over 16 j's)
  v2f U[4][3];            // -2*w1_k*u0[d_k]
  v2f SU[4];              // Sum_k w1_k*u0[d_k]^2
  v2f u1[4], u2[4], c11[4], c12[4];
  #pragma unroll
  for (int ii = 0; ii < 4; ++ii) {
    const int i = i0 + ii;
    float2 u0 = E1p[(0 * BB + i) * HD + lane];
    hb2[lane] = u0;                               // same-wave DS: in-order, no barrier
    SU[ii] = (v2f)0.0f;
    #pragma unroll
    for (int k = 0; k < 3; ++k) {
      v2f a; a.x = hb[I1[k][0]]; a.y = hb[I1[k][1]];
      v2f t = W1[k] * a;
      SU[ii] = FMA2(t, a, SU[ii]);
      U[ii][k] = -2.0f * t;
    }
    u1[ii]  = LD2(E1p, (1 * BB + i) * HD + lane);
    u2[ii]  = LD2(E1p, (2 * BB + i) * HD + lane);
    c11[ii] = LD2(C1p, (0 * BB + i) * HD + lane);
    c12[ii] = LD2(C1p, (1 * BB + i) * HD + lane);
  }

  #pragma unroll 1
  for (int jj = 0; jj < 16; ++jj) {
    const int j = j0 + jj;
    float2 v0 = E2p[(0 * BB + j) * HD + lane];
    hb2[lane] = v0;
    v2f V[3], SV = (v2f)0.0f;
    #pragma unroll
    for (int k = 0; k < 3; ++k) {
      v2f c; c.x = hb[I1[k][0]]; c.y = hb[I1[k][1]];
      V[k] = c;
      SV = FMA2(W1[k] * c, c, SV);
    }
    const v2f v1  = LD2(E2p, (1 * BB + j) * HD + lane);
    const v2f v2  = LD2(E2p, (2 * BB + j) * HD + lane);
    const v2f g21 = LD2(C2p, (0 * BB + j) * HD + lane);
    const v2f g22 = LD2(C2p, (1 * BB + j) * HD + lane);
    #pragma unroll
    for (int ii = 0; ii < 4; ++ii) {
      // layer 1: g from factored gathers (registers only, pk-fma)
      v2f g1 = FMA2(U[ii][0], V[0], FMA2(U[ii][1], V[1], FMA2(U[ii][2], V[2], SU[ii] + SV)));
      v2f d1 = u1[ii] - v1;
      v2f n1 = d1 * d1;
      v2f x1 = FMA2(c11[ii] * g21, Av1, Bv1);
      v2f t1, P1;
      t1.x = __builtin_amdgcn_exp2f(x1.x); t1.y = __builtin_amdgcn_exp2f(x1.y);
      P1.x = __builtin_amdgcn_rcpf(1.0f + t1.x); P1.y = __builtin_amdgcn_rcpf(1.0f + t1.y);
      v2f h1 = FMA2(P1, n1 - g1, g1);           // (1-P)*g + P*n
      // layer 2: per-pair LDS gather (R6/R8-verified float2-store/float-load pattern)
      hb2[lane] = make_float2(h1.x, h1.y);
      v2f g2;
      g2.x = hb[I2[0][0]] * W2[0].x + hb[I2[1][0]] * W2[1].x + hb[I2[2][0]] * W2[2].x;
      g2.y = hb[I2[0][1]] * W2[0].y + hb[I2[1][1]] * W2[1].y + hb[I2[2][1]] * W2[2].y;
      v2f d2 = u2[ii] - v2;
      v2f n2 = d2 * d2;
      v2f x2 = FMA2(c12[ii] * g22, Av2, Bv2);
      v2f t2, P2;
      t2.x = __builtin_amdgcn_exp2f(x2.x); t2.y = __builtin_amdgcn_exp2f(x2.y);
      P2.x = __builtin_amdgcn_rcpf(1.0f + t2.x); P2.y = __builtin_amdgcn_rcpf(1.0f + t2.y);
      v2f h2 = FMA2(P2, n2 - g2, g2);
      // reduce over 128 dims: DPP (VALU pipe), sum lands in lane 63
      float s = dpp_wave_sum_lane63(h2.x + h2.y);
      if (lane == 63) out[(i0 + ii) * BB + j] = s;
    }
  }
}

extern "C" void kernel_launch(void* const* d_in, const int* in_sizes, int n_in,
                              void* d_out, int out_size, void* d_ws, size_t ws_size,
                              hipStream_t stream) {
  (void)in_sizes; (void)n_in; (void)out_size; (void)ws_size;
  // dict order: [0]emb1_0 [1]emb2_0 [2]cert1_0 [3]cert2_0 [4]alpha_0 [5]beta_0
  //             [6..11] layer1, [12..17] layer2, [18]link_0 [19]link_1
  float* ws = (float*)d_ws;
  PackArgs pa;
  pa.src[0] = (const float*)d_in[0];  pa.src[1] = (const float*)d_in[6];  pa.src[2] = (const float*)d_in[12];
  pa.src[3] = (const float*)d_in[1];  pa.src[4] = (const float*)d_in[7];  pa.src[5] = (const float*)d_in[13];
  pa.src[6] = (const float*)d_in[8];  pa.src[7] = (const float*)d_in[14];
  pa.src[8] = (const float*)d_in[9];  pa.src[9] = (const float*)d_in[15];
  hipLaunchKernelGGL(prep_kernel, dim3(1344), dim3(256), 0, stream, pa,
                     (const float*)d_in[18], (const float*)d_in[19],
                     (const float*)d_in[10], (const float*)d_in[11],
                     (const float*)d_in[16], (const float*)d_in[17], ws);
  hipLaunchKernelGGL(main_kernel, dim3(1024), dim3(256), 0, stream,
                     (const float*)ws, (float*)d_out);
}